// Round 1
// baseline (1804.486 us; speedup 1.0000x reference)
//
#include <hip/hip_runtime.h>

typedef __bf16 bf16x8 __attribute__((ext_vector_type(8)));
typedef float f32x4 __attribute__((ext_vector_type(4)));
typedef unsigned short u16;
typedef unsigned int u32;

__device__ __forceinline__ u16 f2b(float f) {
  return __builtin_bit_cast(u16, (__bf16)f);
}
__device__ __forceinline__ float leaky(float x) { return x > 0.f ? x : 0.1f * x; }
__device__ __forceinline__ f32x4 mfma16(bf16x8 a, bf16x8 b, f32x4 c) {
  return __builtin_amdgcn_mfma_f32_16x16x32_bf16(a, b, c, 0, 0, 0);
}

// ---------------- prep: transpose weights to bf16 B^T layouts ----------------
// WT layouts: WT[n][k] = W[k][n]  (so a B-fragment = 8 contiguous bf16)
__global__ void prep_wt(const float* nm_w1, const float* nm_w2,
                        const float* ng_w1, const float* ng_w2,
                        const float* o_w1,
                        u16* wt_nm1, u16* wt_nm2, u16* wt_ng1, u16* wt_ng2,
                        u16* wt_oh) {
  int i = blockIdx.x * blockDim.x + threadIdx.x;
  const int s0 = 64 * 224, s1 = 128 * 64, s2 = 64 * 192, s3 = 128 * 64, s4 = 128 * 128;
  if (i < s0) {
    // nm_w1 rows permuted to [neigh(0:128) | feat(128:192) | pos(192) | zeros]
    int n = i / 224, k = i % 224;
    float v;
    if (k < 128)      v = nm_w1[k * 64 + n];
    else if (k < 192) v = nm_w1[(k + 1) * 64 + n];
    else if (k == 192) v = nm_w1[128 * 64 + n];
    else              v = 0.f;
    wt_nm1[i] = f2b(v);
    return;
  }
  i -= s0;
  if (i < s1) { int n = i / 64, k = i % 64; wt_nm2[i] = f2b(nm_w2[k * 128 + n]); return; }
  i -= s1;
  if (i < s2) { int n = i / 192, k = i % 192; wt_ng1[i] = f2b(ng_w1[k * 64 + n]); return; }
  i -= s2;
  if (i < s3) { int n = i / 64, k = i % 64; wt_ng2[i] = f2b(ng_w2[k * 128 + n]); return; }
  i -= s3;
  if (i < s4) { int n = i / 128, k = i % 128; wt_oh[i] = f2b(o_w1[k * 128 + n]); return; }
}

// G = g_w2 @ o_w1[128:256]  (64x128), bp = o_b1 + g_b2 @ o_w1[128:256]
__global__ void prep_g(const float* g_w2, const float* g_b2, const float* o_w1,
                       const float* o_b1, u16* gt, float* bp) {
  int i = blockIdx.x * blockDim.x + threadIdx.x;
  if (i < 128 * 64) {
    int k = i / 128, c = i % 128;
    float s = 0.f;
    for (int t = 0; t < 128; t++) s += g_w2[k * 128 + t] * o_w1[(128 + t) * 128 + c];
    gt[c * 64 + k] = f2b(s);  // GT[n=c][k]
  } else if (i < 128 * 64 + 128) {
    int c = i - 128 * 64;
    float s = o_b1[c];
    for (int t = 0; t < 128; t++) s += g_b2[t] * o_w1[(128 + t) * 128 + c];
    bp[c] = s;
  }
}

// ---------------- compaction: per-type node lists ----------------
__global__ void k_compact(const int* is_module, int* list_m, int* list_g, int* ctr, int N) {
  int n = blockIdx.x * blockDim.x + threadIdx.x;
  if (n >= N) return;
  if (is_module[n] == 1) list_m[atomicAdd(ctr + 0, 1)] = n;
  else                   list_g[atomicAdd(ctr + 1, 1)] = n;
}

// ---------------- k_pi: h0 = mlp_pi(pi_feat), bf16 out ----------------
__global__ __launch_bounds__(256) void k_pi(const float* pf, const float* w1,
                                            const float* b1, const float* w2,
                                            const float* b2, u16* h0, int N) {
  __shared__ __align__(16) u16 tbuf[4][16 * 64];
  int lane = threadIdx.x & 63, wv = threadIdx.x >> 6;
  int lid = lane & 15, q = lane >> 4;
  int batches = (N + 15) >> 4;
  int w = blockIdx.x * 4 + wv;
  int batch = w < batches ? w : batches - 1;

  // B fragments, registers (loaded once)
  bf16x8 w1f[4];
#pragma unroll
  for (int nt = 0; nt < 4; nt++) {
    bf16x8 f;
#pragma unroll
    for (int j = 0; j < 8; j++) {
      int k = q * 8 + j;
      f[j] = (__bf16)((k < 4) ? w1[k * 64 + nt * 16 + lid] : 0.f);
    }
    w1f[nt] = f;
  }
  bf16x8 w2f[2][8];
#pragma unroll
  for (int kt = 0; kt < 2; kt++)
#pragma unroll
    for (int nt = 0; nt < 8; nt++) {
      bf16x8 f;
#pragma unroll
      for (int j = 0; j < 8; j++)
        f[j] = (__bf16)w2[(kt * 32 + q * 8 + j) * 128 + nt * 16 + lid];
      w2f[kt][nt] = f;
    }

  int id = batch * 16 + lid; if (id >= N) id = N - 1;
  bf16x8 a;
#pragma unroll
  for (int j = 0; j < 8; j++)
    a[j] = (__bf16)((q == 0 && j < 4) ? pf[(size_t)id * 4 + j] : 0.f);

  f32x4 z[4];
#pragma unroll
  for (int nt = 0; nt < 4; nt++) {
    f32x4 c = {0.f, 0.f, 0.f, 0.f};
    z[nt] = mfma16(a, w1f[nt], c);
  }
#pragma unroll
  for (int nt = 0; nt < 4; nt++) {
    float bb = b1[nt * 16 + lid];
#pragma unroll
    for (int r = 0; r < 4; r++)
      tbuf[wv][(q * 4 + r) * 64 + nt * 16 + lid] = f2b(leaky(z[nt][r] + bb));
  }
  __syncthreads();
  bf16x8 a20 = *(const bf16x8*)&tbuf[wv][lid * 64 + q * 8];
  bf16x8 a21 = *(const bf16x8*)&tbuf[wv][lid * 64 + 32 + q * 8];
#pragma unroll
  for (int nt = 0; nt < 8; nt++) {
    f32x4 c = {0.f, 0.f, 0.f, 0.f};
    c = mfma16(a20, w2f[0][nt], c);
    c = mfma16(a21, w2f[1][nt], c);
    float bb = b2[nt * 16 + lid];
#pragma unroll
    for (int r = 0; r < 4; r++) {
      int idr = batch * 16 + q * 4 + r; if (idr >= N) idr = N - 1;
      h0[(size_t)idr * 128 + nt * 16 + lid] = f2b(c[r] + bb);
    }
  }
}

// ---------------- k_edge: filtered scatter-add aggregation ----------------
__global__ void k_edge(const u16* h0, const int* src_m, const int* dst_m,
                       const int* src_g, const int* dst_g, const int* is_module,
                       const float* bitpos, float* acc, float* cnt, float* pos,
                       int E) {
  int lane = threadIdx.x & 63;
  int gw = (blockIdx.x * blockDim.x + threadIdx.x) >> 6;
  int nw = (gridDim.x * blockDim.x) >> 6;
  int tot = 2 * E;
  for (int e = gw; e < tot; e += nw) {
    int s, d, i; bool mod = e < E;
    if (mod) { i = e;     s = src_m[i]; d = dst_m[i]; if (is_module[d] != 1) continue; }
    else     { i = e - E; s = src_g[i]; d = dst_g[i]; if (is_module[d] == 1) continue; }
    u32 pk = *(const u32*)&h0[(size_t)s * 128 + lane * 2];
    float v0 = __builtin_bit_cast(float, pk << 16);
    float v1 = __builtin_bit_cast(float, pk & 0xffff0000u);
    atomicAdd(&acc[(size_t)d * 128 + lane * 2], v0);
    atomicAdd(&acc[(size_t)d * 128 + lane * 2 + 1], v1);
    if (lane == 0) {
      atomicAdd(&cnt[d], 1.f);
      if (mod) atomicAdd(&pos[d], bitpos[i]);
    }
  }
}

// ---------------- k_neigh: per-type neighbor MLP -> h (bf16) ----------------
template <int NKT, bool HASPOS>
__global__ __launch_bounds__(256) void k_neigh(const u16* wt1g, const u16* wt2g,
                                               const float* b1, const float* b2,
                                               const float* feat, const float* acc,
                                               const float* cntv, const float* posv,
                                               const int* list, const int* ctr, int ctr_idx,
                                               const int* is_po, u16* hout) {
  constexpr int KW = NKT * 32;  // 224 (module) or 192 (gate)
  __shared__ __align__(16) u16 wt1[64 * 224];
  __shared__ __align__(16) u16 wt2[128 * 64];
  __shared__ __align__(16) u16 tbuf[4][16 * 64];
  for (int i = threadIdx.x; i < 64 * KW / 2; i += 256) ((u32*)wt1)[i] = ((const u32*)wt1g)[i];
  for (int i = threadIdx.x; i < 128 * 64 / 2; i += 256) ((u32*)wt2)[i] = ((const u32*)wt2g)[i];
  __syncthreads();
  int cntn = ctr[ctr_idx];
  if (cntn == 0) return;
  int lane = threadIdx.x & 63, wv = threadIdx.x >> 6;
  int lid = lane & 15, q = lane >> 4;
  int S = gridDim.x * 4;
  int w = blockIdx.x * 4 + wv;
  int nb = (cntn + 15) / 16;
  int nbp = ((nb + S - 1) / S) * S;

  for (int b = w; b < nbp; b += S) {
    int bb = b < nb ? b : nb - 1;
    int ii0 = bb * 16 + lid;
    int id = list[ii0 < cntn ? ii0 : cntn - 1];
    float inv = 1.f / fmaxf(cntv[id], 1.f);
    float pm = HASPOS ? posv[id] * inv : 0.f;

    f32x4 z[4];
#pragma unroll
    for (int nt = 0; nt < 4; nt++) z[nt] = (f32x4){0.f, 0.f, 0.f, 0.f};

#pragma unroll
    for (int kt = 0; kt < NKT; kt++) {
      int k0 = kt * 32 + q * 8;
      bf16x8 a;
      if (kt < 4) {
        const float4* p = (const float4*)(acc + (size_t)id * 128 + k0);
        float4 xa = p[0], xb = p[1];
        a[0] = (__bf16)(xa.x * inv); a[1] = (__bf16)(xa.y * inv);
        a[2] = (__bf16)(xa.z * inv); a[3] = (__bf16)(xa.w * inv);
        a[4] = (__bf16)(xb.x * inv); a[5] = (__bf16)(xb.y * inv);
        a[6] = (__bf16)(xb.z * inv); a[7] = (__bf16)(xb.w * inv);
      } else if (kt < 6) {
        const float4* p = (const float4*)(feat + (size_t)id * 64 + (k0 - 128));
        float4 xa = p[0], xb = p[1];
        a[0] = (__bf16)xa.x; a[1] = (__bf16)xa.y; a[2] = (__bf16)xa.z; a[3] = (__bf16)xa.w;
        a[4] = (__bf16)xb.x; a[5] = (__bf16)xb.y; a[6] = (__bf16)xb.z; a[7] = (__bf16)xb.w;
      } else {
#pragma unroll
        for (int j = 0; j < 8; j++) a[j] = (__bf16)0.f;
        if (q == 0) a[0] = (__bf16)pm;
      }
#pragma unroll
      for (int nt = 0; nt < 4; nt++) {
        bf16x8 bf = *(const bf16x8*)&wt1[(nt * 16 + lid) * KW + k0];
        z[nt] = mfma16(a, bf, z[nt]);
      }
    }
    // bias + leaky + transpose to A-layout
#pragma unroll
    for (int nt = 0; nt < 4; nt++) {
      float bb1 = b1[nt * 16 + lid];
#pragma unroll
      for (int r = 0; r < 4; r++)
        tbuf[wv][(q * 4 + r) * 64 + nt * 16 + lid] = f2b(leaky(z[nt][r] + bb1));
    }
    __syncthreads();
    bf16x8 a20 = *(const bf16x8*)&tbuf[wv][lid * 64 + q * 8];
    bf16x8 a21 = *(const bf16x8*)&tbuf[wv][lid * 64 + 32 + q * 8];
    f32x4 hv[8];
#pragma unroll
    for (int nt = 0; nt < 8; nt++) {
      f32x4 c = {0.f, 0.f, 0.f, 0.f};
      c = mfma16(a20, *(const bf16x8*)&wt2[(nt * 16 + lid) * 64 + q * 8], c);
      c = mfma16(a21, *(const bf16x8*)&wt2[(nt * 16 + lid) * 64 + 32 + q * 8], c);
      hv[nt] = c;
    }
    int idr_[4]; bool kp_[4];
#pragma unroll
    for (int r = 0; r < 4; r++) {
      int ii = bb * 16 + q * 4 + r;
      idr_[r] = list[ii < cntn ? ii : cntn - 1];
      kp_[r] = (is_po[idr_[r]] != 1);
    }
#pragma unroll
    for (int nt = 0; nt < 8; nt++) {
      float bb2 = b2[nt * 16 + lid];
#pragma unroll
      for (int r = 0; r < 4; r++) {
        float v = hv[nt][r] + bb2;
        if (kp_[r]) v = fmaxf(v, 0.f);
        hout[(size_t)idr_[r] * 128 + nt * 16 + lid] = f2b(v);
      }
    }
  }
}

// ---------------- k_out: z = h@o_w1[:128] + a2g@G + bp; out = leaky(z)@o_w2 + o_b2
__global__ __launch_bounds__(256) void k_out(const u16* h, const float* level,
                                             const float* g_w1, const float* g_b1,
                                             const u16* wt_oh_g, const u16* gt_g,
                                             const float* bp_g, const float* o_w2,
                                             const float* o_b2, float* out, int N) {
  __shared__ __align__(16) u16 wt_oh[128 * 128];
  __shared__ __align__(16) u16 gt[128 * 64];
  for (int i = threadIdx.x; i < 128 * 128 / 2; i += 256) ((u32*)wt_oh)[i] = ((const u32*)wt_oh_g)[i];
  for (int i = threadIdx.x; i < 128 * 64 / 2; i += 256) ((u32*)gt)[i] = ((const u32*)gt_g)[i];
  __syncthreads();
  int lane = threadIdx.x & 63, wv = threadIdx.x >> 6;
  int lid = lane & 15, q = lane >> 4;
  int batches = (N + 15) >> 4;
  int w = blockIdx.x * 4 + wv;
  int batch = w < batches ? w : batches - 1;

  float gw[2][8], gb[2][8];
#pragma unroll
  for (int kt = 0; kt < 2; kt++)
#pragma unroll
    for (int j = 0; j < 8; j++) {
      int k = kt * 32 + q * 8 + j;
      gw[kt][j] = g_w1[k]; gb[kt][j] = g_b1[k];
    }
  float w2o[8], bpv[8];
#pragma unroll
  for (int nt = 0; nt < 8; nt++) { w2o[nt] = o_w2[nt * 16 + lid]; bpv[nt] = bp_g[nt * 16 + lid]; }
  float ob2 = o_b2[0];

  int id = batch * 16 + lid; if (id >= N) id = N - 1;
  float lv = level[id];
  bf16x8 ah[4];
#pragma unroll
  for (int kt = 0; kt < 4; kt++)
    ah[kt] = *(const bf16x8*)(h + (size_t)id * 128 + kt * 32 + q * 8);
  bf16x8 ag[2];
#pragma unroll
  for (int kt = 0; kt < 2; kt++)
#pragma unroll
    for (int j = 0; j < 8; j++)
      ag[kt][j] = (__bf16)leaky(lv * gw[kt][j] + gb[kt][j]);

  f32x4 accv[8];
#pragma unroll
  for (int nt = 0; nt < 8; nt++) {
    f32x4 c = {0.f, 0.f, 0.f, 0.f};
#pragma unroll
    for (int kt = 0; kt < 4; kt++)
      c = mfma16(ah[kt], *(const bf16x8*)&wt_oh[(nt * 16 + lid) * 128 + kt * 32 + q * 8], c);
#pragma unroll
    for (int kt = 0; kt < 2; kt++)
      c = mfma16(ag[kt], *(const bf16x8*)&gt[(nt * 16 + lid) * 64 + kt * 32 + q * 8], c);
    accv[nt] = c;
  }
  float p[4];
#pragma unroll
  for (int r = 0; r < 4; r++) {
    float s = 0.f;
#pragma unroll
    for (int nt = 0; nt < 8; nt++) s += leaky(accv[nt][r] + bpv[nt]) * w2o[nt];
    p[r] = s;
  }
#pragma unroll
  for (int r = 0; r < 4; r++)
#pragma unroll
    for (int off = 1; off < 16; off <<= 1) p[r] += __shfl_xor(p[r], off, 16);
  if (lid == 0) {
#pragma unroll
    for (int r = 0; r < 4; r++) {
      int idr = batch * 16 + q * 4 + r; if (idr >= N) idr = N - 1;
      out[idr] = p[r] + ob2;
    }
  }
}

extern "C" void kernel_launch(void* const* d_in, const int* in_sizes, int n_in,
                              void* d_out, int out_size, void* d_ws, size_t ws_size,
                              hipStream_t stream) {
  const float* feat = (const float*)d_in[0];
  const float* pi_feat = (const float*)d_in[1];
  const float* level = (const float*)d_in[2];
  const float* bitpos = (const float*)d_in[3];
  const int* is_po = (const int*)d_in[4];
  const int* is_module = (const int*)d_in[5];
  const int* src_m = (const int*)d_in[6];
  const int* dst_m = (const int*)d_in[7];
  const int* src_g = (const int*)d_in[8];
  const int* dst_g = (const int*)d_in[9];
  const float* pi_w1 = (const float*)d_in[10];
  const float* pi_b1 = (const float*)d_in[11];
  const float* pi_w2 = (const float*)d_in[12];
  const float* pi_b2 = (const float*)d_in[13];
  const float* nm_w1 = (const float*)d_in[14];
  const float* nm_b1 = (const float*)d_in[15];
  const float* nm_w2 = (const float*)d_in[16];
  const float* nm_b2 = (const float*)d_in[17];
  const float* ng_w1 = (const float*)d_in[18];
  const float* ng_b1 = (const float*)d_in[19];
  const float* ng_w2 = (const float*)d_in[20];
  const float* ng_b2 = (const float*)d_in[21];
  const float* g_w1 = (const float*)d_in[22];
  const float* g_b1 = (const float*)d_in[23];
  const float* g_w2 = (const float*)d_in[24];
  const float* g_b2 = (const float*)d_in[25];
  const float* o_w1 = (const float*)d_in[26];
  const float* o_b1 = (const float*)d_in[27];
  const float* o_w2 = (const float*)d_in[28];
  const float* o_b2 = (const float*)d_in[29];

  int N = in_sizes[0] / 64;
  int E = in_sizes[3];

  char* ws = (char*)d_ws;
  size_t off = 0;
  auto alloc = [&](size_t bytes) {
    char* p = ws + off;
    off += (bytes + 15) & ~(size_t)15;
    return p;
  };
  float* acc = (float*)alloc((size_t)N * 128 * 4);
  float* cnt = (float*)alloc((size_t)N * 4);
  float* pos = (float*)alloc((size_t)N * 4);
  int* ctr = (int*)alloc(16);
  size_t zero_bytes = off;
  u16* h0 = (u16*)alloc((size_t)N * 128 * 2);
  u16* h = (u16*)alloc((size_t)N * 128 * 2);
  int* lm = (int*)alloc((size_t)N * 4);
  int* lg = (int*)alloc((size_t)N * 4);
  u16* wt_nm1 = (u16*)alloc(64 * 224 * 2);
  u16* wt_nm2 = (u16*)alloc(128 * 64 * 2);
  u16* wt_ng1 = (u16*)alloc(64 * 192 * 2);
  u16* wt_ng2 = (u16*)alloc(128 * 64 * 2);
  u16* wt_oh = (u16*)alloc(128 * 128 * 2);
  u16* gt = (u16*)alloc(128 * 64 * 2);
  float* bp = (float*)alloc(128 * 4);

  hipMemsetAsync(d_ws, 0, zero_bytes, stream);
  prep_wt<<<232, 256, 0, stream>>>(nm_w1, nm_w2, ng_w1, ng_w2, o_w1,
                                   wt_nm1, wt_nm2, wt_ng1, wt_ng2, wt_oh);
  prep_g<<<33, 256, 0, stream>>>(g_w2, g_b2, o_w1, o_b1, gt, bp);
  k_compact<<<(N + 255) / 256, 256, 0, stream>>>(is_module, lm, lg, ctr, N);
  int batches = (N + 15) / 16;
  int mblocks = (batches + 3) / 4;
  k_pi<<<mblocks, 256, 0, stream>>>(pi_feat, pi_w1, pi_b1, pi_w2, pi_b2, h0, N);
  k_edge<<<2048, 256, 0, stream>>>(h0, src_m, dst_m, src_g, dst_g, is_module,
                                   bitpos, acc, cnt, pos, E);
  k_neigh<7, true><<<mblocks, 256, 0, stream>>>(wt_nm1, wt_nm2, nm_b1, nm_b2, feat,
                                                acc, cnt, pos, lm, ctr, 0, is_po, h);
  k_neigh<6, false><<<mblocks, 256, 0, stream>>>(wt_ng1, wt_ng2, ng_b1, ng_b2, feat,
                                                 acc, cnt, pos, lg, ctr, 1, is_po, h);
  k_out<<<mblocks, 256, 0, stream>>>(h, level, g_w1, g_b1, wt_oh, gt, bp,
                                     o_w2, o_b2, (float*)d_out, N);
}

// Round 2
// 413.725 us; speedup vs baseline: 4.3616x; 4.3616x over previous
//
#include <hip/hip_runtime.h>

typedef __bf16 bf16x8 __attribute__((ext_vector_type(8)));
typedef float f32x4 __attribute__((ext_vector_type(4)));
typedef unsigned short u16;
typedef unsigned int u32;
typedef unsigned long long u64;

__device__ __forceinline__ u16 f2b(float f) {
  return __builtin_bit_cast(u16, (__bf16)f);
}
__device__ __forceinline__ float leaky(float x) { return x > 0.f ? x : 0.1f * x; }
__device__ __forceinline__ f32x4 mfma16(bf16x8 a, bf16x8 b, f32x4 c) {
  return __builtin_amdgcn_mfma_f32_16x16x32_bf16(a, b, c, 0, 0, 0);
}

// ---------------- prep: transpose weights to bf16 B^T layouts ----------------
__global__ void prep_wt(const float* nm_w1, const float* nm_w2,
                        const float* ng_w1, const float* ng_w2,
                        const float* o_w1,
                        u16* wt_nm1, u16* wt_nm2, u16* wt_ng1, u16* wt_ng2,
                        u16* wt_oh) {
  int i = blockIdx.x * blockDim.x + threadIdx.x;
  const int s0 = 64 * 224, s1 = 128 * 64, s2 = 64 * 192, s3 = 128 * 64, s4 = 128 * 128;
  if (i < s0) {
    int n = i / 224, k = i % 224;
    float v;
    if (k < 128)      v = nm_w1[k * 64 + n];
    else if (k < 192) v = nm_w1[(k + 1) * 64 + n];
    else if (k == 192) v = nm_w1[128 * 64 + n];
    else              v = 0.f;
    wt_nm1[i] = f2b(v);
    return;
  }
  i -= s0;
  if (i < s1) { int n = i / 64, k = i % 64; wt_nm2[i] = f2b(nm_w2[k * 128 + n]); return; }
  i -= s1;
  if (i < s2) { int n = i / 192, k = i % 192; wt_ng1[i] = f2b(ng_w1[k * 64 + n]); return; }
  i -= s2;
  if (i < s3) { int n = i / 64, k = i % 64; wt_ng2[i] = f2b(ng_w2[k * 128 + n]); return; }
  i -= s3;
  if (i < s4) { int n = i / 128, k = i % 128; wt_oh[i] = f2b(o_w1[k * 128 + n]); return; }
}

__global__ void prep_g(const float* g_w2, const float* g_b2, const float* o_w1,
                       const float* o_b1, u16* gt, float* bp) {
  int i = blockIdx.x * blockDim.x + threadIdx.x;
  if (i < 128 * 64) {
    int k = i / 128, c = i % 128;
    float s = 0.f;
    for (int t = 0; t < 128; t++) s += g_w2[k * 128 + t] * o_w1[(128 + t) * 128 + c];
    gt[c * 64 + k] = f2b(s);
  } else if (i < 128 * 64 + 128) {
    int c = i - 128 * 64;
    float s = o_b1[c];
    for (int t = 0; t < 128; t++) s += g_b2[t] * o_w1[(128 + t) * 128 + c];
    bp[c] = s;
  }
}

// ---------------- compaction: block-aggregated ballot (2 atomics/block) -----
__global__ __launch_bounds__(256) void k_compact(const int* is_module, int* list_m,
                                                 int* list_g, int* ctr, int N) {
  __shared__ int wcm[4], wcg[4], base_s[2];
  int n = blockIdx.x * 256 + threadIdx.x;
  int lane = threadIdx.x & 63, wv = threadIdx.x >> 6;
  bool valid = n < N;
  int v = valid ? is_module[n] : -1;
  bool m = valid && (v == 1);
  bool g = valid && (v != 1);
  u64 mm = __ballot(m), gg = __ballot(g);
  if (lane == 0) { wcm[wv] = __popcll(mm); wcg[wv] = __popcll(gg); }
  __syncthreads();
  if (threadIdx.x == 0) {
    base_s[0] = atomicAdd(ctr + 0, wcm[0] + wcm[1] + wcm[2] + wcm[3]);
    base_s[1] = atomicAdd(ctr + 1, wcg[0] + wcg[1] + wcg[2] + wcg[3]);
  }
  __syncthreads();
  int bm = base_s[0], bg = base_s[1];
  for (int i = 0; i < wv; i++) { bm += wcm[i]; bg += wcg[i]; }
  u64 lt = ((u64)1 << lane) - 1;
  if (m) list_m[bm + __popcll(mm & lt)] = n;
  if (g) list_g[bg + __popcll(gg & lt)] = n;
}

// ---------------- CSR build ----------------
__global__ void k_deg(const int* dst_m, const int* dst_g, const int* is_module,
                      int* deg, int E) {
  int e = blockIdx.x * 256 + threadIdx.x;
  if (e < E) {
    int d = dst_m[e];
    if (is_module[d] == 1) atomicAdd(&deg[d], 1);
  } else if (e < 2 * E) {
    int d = dst_g[e - E];
    if (is_module[d] != 1) atomicAdd(&deg[d], 1);
  }
}

// scan1: per-block (1024 elems) exclusive scan + block sums
__global__ __launch_bounds__(256) void k_scan1(const int* deg, int* part, int* bsum, int N) {
  __shared__ int lds[256];
  int t = threadIdx.x;
  int base = blockIdx.x * 1024 + t * 4;
  int v[4];
#pragma unroll
  for (int j = 0; j < 4; j++) v[j] = (base + j < N) ? deg[base + j] : 0;
  int s = v[0] + v[1] + v[2] + v[3];
  lds[t] = s;
  __syncthreads();
  for (int off = 1; off < 256; off <<= 1) {
    int y = (t >= off) ? lds[t - off] : 0;
    __syncthreads();
    lds[t] += y;
    __syncthreads();
  }
  int run = lds[t] - s;  // exclusive prefix of this thread's chunk
#pragma unroll
  for (int j = 0; j < 4; j++) {
    if (base + j < N) part[base + j] = run;
    run += v[j];
  }
  if (t == 255) bsum[blockIdx.x] = lds[255];
}

// scan2: single block scans block sums (nb <= 256); writes rowptr[N] = total
__global__ __launch_bounds__(256) void k_scan2(int* bsum, int* rowptr, int nb, int N) {
  __shared__ int lds[256];
  int t = threadIdx.x;
  int s = (t < nb) ? bsum[t] : 0;
  lds[t] = s;
  __syncthreads();
  for (int off = 1; off < 256; off <<= 1) {
    int y = (t >= off) ? lds[t - off] : 0;
    __syncthreads();
    lds[t] += y;
    __syncthreads();
  }
  if (t < nb) bsum[t] = lds[t] - s;
  if (t == 255) rowptr[N] = lds[255];
}

__global__ void k_scan3(const int* part, const int* bsum, int* rowptr, int* cursor, int N) {
  int i = blockIdx.x * 256 + threadIdx.x;
  if (i < N) {
    int v = part[i] + bsum[i >> 10];
    rowptr[i] = v;
    cursor[i] = v;
  }
}

__global__ void k_scatter(const int* src_m, const int* dst_m, const int* src_g,
                          const int* dst_g, const int* is_module, const float* bitpos,
                          int* cursor, int* csr_src, float* csr_pos, int E) {
  int e = blockIdx.x * 256 + threadIdx.x;
  if (e < E) {
    int d = dst_m[e];
    if (is_module[d] == 1) {
      int p = atomicAdd(&cursor[d], 1);
      csr_src[p] = src_m[e];
      csr_pos[p] = bitpos[e];
    }
  } else if (e < 2 * E) {
    int d = dst_g[e - E];
    if (is_module[d] != 1) {
      int p = atomicAdd(&cursor[d], 1);
      csr_src[p] = src_g[e - E];
    }
  }
}

// ---------------- k_gather: one wave per node, mean of h0 rows -> hbar bf16 --
__global__ __launch_bounds__(256) void k_gather(const u16* h0, const int* rowptr,
                                                const int* csr_src, const float* csr_pos,
                                                const int* is_module, u16* hbar,
                                                float* posbar, int N) {
  int n = (blockIdx.x * 256 + threadIdx.x) >> 6;
  int lane = threadIdx.x & 63;
  if (n >= N) return;
  int beg = rowptr[n], end = rowptr[n + 1];
  bool mod = (is_module[n] == 1);
  float a0 = 0.f, a1 = 0.f, ps = 0.f;
  for (int j0 = beg; j0 < end; j0 += 64) {
    int jn = end - j0; if (jn > 64) jn = 64;
    int sv = (j0 + lane < end) ? csr_src[j0 + lane] : 0;
    if (mod && j0 + lane < end) ps += csr_pos[j0 + lane];
    for (int j = 0; j < jn; j++) {
      int s = __shfl(sv, j);
      u32 pk = *(const u32*)&h0[(size_t)s * 128 + lane * 2];
      a0 += __builtin_bit_cast(float, pk << 16);
      a1 += __builtin_bit_cast(float, pk & 0xffff0000u);
    }
  }
  int deg = end - beg;
  float inv = 1.f / (float)(deg > 1 ? deg : 1);
  u32 outp = (u32)f2b(a0 * inv) | ((u32)f2b(a1 * inv) << 16);
  ((u32*)hbar)[(size_t)n * 64 + lane] = outp;
  if (mod) {
#pragma unroll
    for (int off = 1; off < 64; off <<= 1) ps += __shfl_xor(ps, off);
    if (lane == 0) posbar[n] = ps * inv;
  }
}

// ---------------- k_pi: h0 = mlp_pi(pi_feat), bf16 out ----------------
__global__ __launch_bounds__(256) void k_pi(const float* pf, const float* w1,
                                            const float* b1, const float* w2,
                                            const float* b2, u16* h0, int N) {
  __shared__ __align__(16) u16 tbuf[4][16 * 64];
  int lane = threadIdx.x & 63, wv = threadIdx.x >> 6;
  int lid = lane & 15, q = lane >> 4;
  int batches = (N + 15) >> 4;
  int w = blockIdx.x * 4 + wv;
  int batch = w < batches ? w : batches - 1;

  bf16x8 w1f[4];
#pragma unroll
  for (int nt = 0; nt < 4; nt++) {
    bf16x8 f;
#pragma unroll
    for (int j = 0; j < 8; j++) {
      int k = q * 8 + j;
      f[j] = (__bf16)((k < 4) ? w1[k * 64 + nt * 16 + lid] : 0.f);
    }
    w1f[nt] = f;
  }
  bf16x8 w2f[2][8];
#pragma unroll
  for (int kt = 0; kt < 2; kt++)
#pragma unroll
    for (int nt = 0; nt < 8; nt++) {
      bf16x8 f;
#pragma unroll
      for (int j = 0; j < 8; j++)
        f[j] = (__bf16)w2[(kt * 32 + q * 8 + j) * 128 + nt * 16 + lid];
      w2f[kt][nt] = f;
    }

  int id = batch * 16 + lid; if (id >= N) id = N - 1;
  bf16x8 a;
#pragma unroll
  for (int j = 0; j < 8; j++)
    a[j] = (__bf16)((q == 0 && j < 4) ? pf[(size_t)id * 4 + j] : 0.f);

  f32x4 z[4];
#pragma unroll
  for (int nt = 0; nt < 4; nt++) {
    f32x4 c = {0.f, 0.f, 0.f, 0.f};
    z[nt] = mfma16(a, w1f[nt], c);
  }
#pragma unroll
  for (int nt = 0; nt < 4; nt++) {
    float bb = b1[nt * 16 + lid];
#pragma unroll
    for (int r = 0; r < 4; r++)
      tbuf[wv][(q * 4 + r) * 64 + nt * 16 + lid] = f2b(leaky(z[nt][r] + bb));
  }
  __syncthreads();
  bf16x8 a20 = *(const bf16x8*)&tbuf[wv][lid * 64 + q * 8];
  bf16x8 a21 = *(const bf16x8*)&tbuf[wv][lid * 64 + 32 + q * 8];
#pragma unroll
  for (int nt = 0; nt < 8; nt++) {
    f32x4 c = {0.f, 0.f, 0.f, 0.f};
    c = mfma16(a20, w2f[0][nt], c);
    c = mfma16(a21, w2f[1][nt], c);
    float bb = b2[nt * 16 + lid];
#pragma unroll
    for (int r = 0; r < 4; r++) {
      int idr = batch * 16 + q * 4 + r; if (idr >= N) idr = N - 1;
      h0[(size_t)idr * 128 + nt * 16 + lid] = f2b(c[r] + bb);
    }
  }
}

// ---------------- k_neigh: per-type neighbor MLP -> h (bf16) ----------------
template <int NKT, bool HASPOS>
__global__ __launch_bounds__(256) void k_neigh(const u16* wt1g, const u16* wt2g,
                                               const float* b1, const float* b2,
                                               const float* feat, const u16* hbar,
                                               const float* posbar,
                                               const int* list, const int* ctr, int ctr_idx,
                                               const int* is_po, u16* hout) {
  constexpr int KW = NKT * 32;  // 224 (module) or 192 (gate)
  __shared__ __align__(16) u16 wt1[64 * 224];
  __shared__ __align__(16) u16 wt2[128 * 64];
  __shared__ __align__(16) u16 tbuf[4][16 * 64];
  for (int i = threadIdx.x; i < 64 * KW / 2; i += 256) ((u32*)wt1)[i] = ((const u32*)wt1g)[i];
  for (int i = threadIdx.x; i < 128 * 64 / 2; i += 256) ((u32*)wt2)[i] = ((const u32*)wt2g)[i];
  __syncthreads();
  int cntn = ctr[ctr_idx];
  if (cntn == 0) return;
  int lane = threadIdx.x & 63, wv = threadIdx.x >> 6;
  int lid = lane & 15, q = lane >> 4;
  int S = gridDim.x * 4;
  int w = blockIdx.x * 4 + wv;
  int nb = (cntn + 15) / 16;
  int nbp = ((nb + S - 1) / S) * S;

  for (int b = w; b < nbp; b += S) {
    int bb = b < nb ? b : nb - 1;
    int ii0 = bb * 16 + lid;
    int id = list[ii0 < cntn ? ii0 : cntn - 1];
    float pm = HASPOS ? posbar[id] : 0.f;

    f32x4 z[4];
#pragma unroll
    for (int nt = 0; nt < 4; nt++) z[nt] = (f32x4){0.f, 0.f, 0.f, 0.f};

#pragma unroll
    for (int kt = 0; kt < NKT; kt++) {
      int k0 = kt * 32 + q * 8;
      bf16x8 a;
      if (kt < 4) {
        a = *(const bf16x8*)(hbar + (size_t)id * 128 + k0);
      } else if (kt < 6) {
        const float4* p = (const float4*)(feat + (size_t)id * 64 + (k0 - 128));
        float4 xa = p[0], xb = p[1];
        a[0] = (__bf16)xa.x; a[1] = (__bf16)xa.y; a[2] = (__bf16)xa.z; a[3] = (__bf16)xa.w;
        a[4] = (__bf16)xb.x; a[5] = (__bf16)xb.y; a[6] = (__bf16)xb.z; a[7] = (__bf16)xb.w;
      } else {
#pragma unroll
        for (int j = 0; j < 8; j++) a[j] = (__bf16)0.f;
        if (q == 0) a[0] = (__bf16)pm;
      }
#pragma unroll
      for (int nt = 0; nt < 4; nt++) {
        bf16x8 bf = *(const bf16x8*)&wt1[(nt * 16 + lid) * KW + k0];
        z[nt] = mfma16(a, bf, z[nt]);
      }
    }
#pragma unroll
    for (int nt = 0; nt < 4; nt++) {
      float bb1 = b1[nt * 16 + lid];
#pragma unroll
      for (int r = 0; r < 4; r++)
        tbuf[wv][(q * 4 + r) * 64 + nt * 16 + lid] = f2b(leaky(z[nt][r] + bb1));
    }
    __syncthreads();
    bf16x8 a20 = *(const bf16x8*)&tbuf[wv][lid * 64 + q * 8];
    bf16x8 a21 = *(const bf16x8*)&tbuf[wv][lid * 64 + 32 + q * 8];
    f32x4 hv[8];
#pragma unroll
    for (int nt = 0; nt < 8; nt++) {
      f32x4 c = {0.f, 0.f, 0.f, 0.f};
      c = mfma16(a20, *(const bf16x8*)&wt2[(nt * 16 + lid) * 64 + q * 8], c);
      c = mfma16(a21, *(const bf16x8*)&wt2[(nt * 16 + lid) * 64 + 32 + q * 8], c);
      hv[nt] = c;
    }
    int idr_[4]; bool kp_[4];
#pragma unroll
    for (int r = 0; r < 4; r++) {
      int ii = bb * 16 + q * 4 + r;
      idr_[r] = list[ii < cntn ? ii : cntn - 1];
      kp_[r] = (is_po[idr_[r]] != 1);
    }
#pragma unroll
    for (int nt = 0; nt < 8; nt++) {
      float bb2 = b2[nt * 16 + lid];
#pragma unroll
      for (int r = 0; r < 4; r++) {
        float v = hv[nt][r] + bb2;
        if (kp_[r]) v = fmaxf(v, 0.f);
        hout[(size_t)idr_[r] * 128 + nt * 16 + lid] = f2b(v);
      }
    }
  }
}

// ---------------- k_out ----------------
__global__ __launch_bounds__(256) void k_out(const u16* h, const float* level,
                                             const float* g_w1, const float* g_b1,
                                             const u16* wt_oh_g, const u16* gt_g,
                                             const float* bp_g, const float* o_w2,
                                             const float* o_b2, float* out, int N) {
  __shared__ __align__(16) u16 wt_oh[128 * 128];
  __shared__ __align__(16) u16 gt[128 * 64];
  for (int i = threadIdx.x; i < 128 * 128 / 2; i += 256) ((u32*)wt_oh)[i] = ((const u32*)wt_oh_g)[i];
  for (int i = threadIdx.x; i < 128 * 64 / 2; i += 256) ((u32*)gt)[i] = ((const u32*)gt_g)[i];
  __syncthreads();
  int lane = threadIdx.x & 63, wv = threadIdx.x >> 6;
  int lid = lane & 15, q = lane >> 4;
  int batches = (N + 15) >> 4;
  int w = blockIdx.x * 4 + wv;
  int batch = w < batches ? w : batches - 1;

  float gw[2][8], gb[2][8];
#pragma unroll
  for (int kt = 0; kt < 2; kt++)
#pragma unroll
    for (int j = 0; j < 8; j++) {
      int k = kt * 32 + q * 8 + j;
      gw[kt][j] = g_w1[k]; gb[kt][j] = g_b1[k];
    }
  float w2o[8], bpv[8];
#pragma unroll
  for (int nt = 0; nt < 8; nt++) { w2o[nt] = o_w2[nt * 16 + lid]; bpv[nt] = bp_g[nt * 16 + lid]; }
  float ob2 = o_b2[0];

  int id = batch * 16 + lid; if (id >= N) id = N - 1;
  float lv = level[id];
  bf16x8 ah[4];
#pragma unroll
  for (int kt = 0; kt < 4; kt++)
    ah[kt] = *(const bf16x8*)(h + (size_t)id * 128 + kt * 32 + q * 8);
  bf16x8 ag[2];
#pragma unroll
  for (int kt = 0; kt < 2; kt++)
#pragma unroll
    for (int j = 0; j < 8; j++)
      ag[kt][j] = (__bf16)leaky(lv * gw[kt][j] + gb[kt][j]);

  f32x4 accv[8];
#pragma unroll
  for (int nt = 0; nt < 8; nt++) {
    f32x4 c = {0.f, 0.f, 0.f, 0.f};
#pragma unroll
    for (int kt = 0; kt < 4; kt++)
      c = mfma16(ah[kt], *(const bf16x8*)&wt_oh[(nt * 16 + lid) * 128 + kt * 32 + q * 8], c);
#pragma unroll
    for (int kt = 0; kt < 2; kt++)
      c = mfma16(ag[kt], *(const bf16x8*)&gt[(nt * 16 + lid) * 64 + kt * 32 + q * 8], c);
    accv[nt] = c;
  }
  float p[4];
#pragma unroll
  for (int r = 0; r < 4; r++) {
    float s = 0.f;
#pragma unroll
    for (int nt = 0; nt < 8; nt++) s += leaky(accv[nt][r] + bpv[nt]) * w2o[nt];
    p[r] = s;
  }
#pragma unroll
  for (int r = 0; r < 4; r++)
#pragma unroll
    for (int off = 1; off < 16; off <<= 1) p[r] += __shfl_xor(p[r], off, 16);
  if (lid == 0) {
#pragma unroll
    for (int r = 0; r < 4; r++) {
      int idr = batch * 16 + q * 4 + r; if (idr >= N) idr = N - 1;
      out[idr] = p[r] + ob2;
    }
  }
}

extern "C" void kernel_launch(void* const* d_in, const int* in_sizes, int n_in,
                              void* d_out, int out_size, void* d_ws, size_t ws_size,
                              hipStream_t stream) {
  const float* feat = (const float*)d_in[0];
  const float* pi_feat = (const float*)d_in[1];
  const float* level = (const float*)d_in[2];
  const float* bitpos = (const float*)d_in[3];
  const int* is_po = (const int*)d_in[4];
  const int* is_module = (const int*)d_in[5];
  const int* src_m = (const int*)d_in[6];
  const int* dst_m = (const int*)d_in[7];
  const int* src_g = (const int*)d_in[8];
  const int* dst_g = (const int*)d_in[9];
  const float* pi_w1 = (const float*)d_in[10];
  const float* pi_b1 = (const float*)d_in[11];
  const float* pi_w2 = (const float*)d_in[12];
  const float* pi_b2 = (const float*)d_in[13];
  const float* nm_w1 = (const float*)d_in[14];
  const float* nm_b1 = (const float*)d_in[15];
  const float* nm_w2 = (const float*)d_in[16];
  const float* nm_b2 = (const float*)d_in[17];
  const float* ng_w1 = (const float*)d_in[18];
  const float* ng_b1 = (const float*)d_in[19];
  const float* ng_w2 = (const float*)d_in[20];
  const float* ng_b2 = (const float*)d_in[21];
  const float* g_w1 = (const float*)d_in[22];
  const float* g_b1 = (const float*)d_in[23];
  const float* g_w2 = (const float*)d_in[24];
  const float* g_b2 = (const float*)d_in[25];
  const float* o_w1 = (const float*)d_in[26];
  const float* o_b1 = (const float*)d_in[27];
  const float* o_w2 = (const float*)d_in[28];
  const float* o_b2 = (const float*)d_in[29];

  int N = in_sizes[0] / 64;
  int E = in_sizes[3];

  char* ws = (char*)d_ws;
  size_t off = 0;
  auto alloc = [&](size_t bytes) {
    char* p = ws + off;
    off += (bytes + 255) & ~(size_t)255;
    return p;
  };
  // zero-init region
  int* deg = (int*)alloc((size_t)N * 4);
  int* ctr = (int*)alloc(16);
  size_t zero_bytes = off;
  // non-zeroed scratch
  int* part = (int*)alloc((size_t)N * 4);
  int* bsum = (int*)alloc(256 * 4);
  int* rowptr = (int*)alloc(((size_t)N + 1) * 4);
  int* cursor = (int*)alloc((size_t)N * 4);
  int* csr_src = (int*)alloc((size_t)2 * E * 4);
  float* csr_pos = (float*)alloc((size_t)2 * E * 4);
  u16* h0 = (u16*)alloc((size_t)N * 128 * 2);
  u16* hbar = (u16*)alloc((size_t)N * 128 * 2);
  float* posbar = (float*)alloc((size_t)N * 4);
  u16* h = (u16*)alloc((size_t)N * 128 * 2);
  int* lm = (int*)alloc((size_t)N * 4);
  int* lg = (int*)alloc((size_t)N * 4);
  u16* wt_nm1 = (u16*)alloc(64 * 224 * 2);
  u16* wt_nm2 = (u16*)alloc(128 * 64 * 2);
  u16* wt_ng1 = (u16*)alloc(64 * 192 * 2);
  u16* wt_ng2 = (u16*)alloc(128 * 64 * 2);
  u16* wt_oh = (u16*)alloc(128 * 128 * 2);
  u16* gt = (u16*)alloc(128 * 64 * 2);
  float* bp = (float*)alloc(128 * 4);

  hipMemsetAsync(d_ws, 0, zero_bytes, stream);
  prep_wt<<<232, 256, 0, stream>>>(nm_w1, nm_w2, ng_w1, ng_w2, o_w1,
                                   wt_nm1, wt_nm2, wt_ng1, wt_ng2, wt_oh);
  prep_g<<<33, 256, 0, stream>>>(g_w2, g_b2, o_w1, o_b1, gt, bp);
  k_compact<<<(N + 255) / 256, 256, 0, stream>>>(is_module, lm, lg, ctr, N);
  // CSR build
  int nb = (N + 1023) / 1024;
  k_deg<<<(2 * E + 255) / 256, 256, 0, stream>>>(dst_m, dst_g, is_module, deg, E);
  k_scan1<<<nb, 256, 0, stream>>>(deg, part, bsum, N);
  k_scan2<<<1, 256, 0, stream>>>(bsum, rowptr, nb, N);
  k_scan3<<<(N + 255) / 256, 256, 0, stream>>>(part, bsum, rowptr, cursor, N);
  k_scatter<<<(2 * E + 255) / 256, 256, 0, stream>>>(src_m, dst_m, src_g, dst_g,
                                                     is_module, bitpos, cursor,
                                                     csr_src, csr_pos, E);
  int batches = (N + 15) / 16;
  int mblocks = (batches + 3) / 4;
  k_pi<<<mblocks, 256, 0, stream>>>(pi_feat, pi_w1, pi_b1, pi_w2, pi_b2, h0, N);
  k_gather<<<(N * 64 + 255) / 256, 256, 0, stream>>>(h0, rowptr, csr_src, csr_pos,
                                                     is_module, hbar, posbar, N);
  k_neigh<7, true><<<mblocks, 256, 0, stream>>>(wt_nm1, wt_nm2, nm_b1, nm_b2, feat,
                                                hbar, posbar, lm, ctr, 0, is_po, h);
  k_neigh<6, false><<<mblocks, 256, 0, stream>>>(wt_ng1, wt_ng2, ng_b1, ng_b2, feat,
                                                 hbar, posbar, lg, ctr, 1, is_po, h);
  k_out<<<mblocks, 256, 0, stream>>>(h, level, g_w1, g_b1, wt_oh, gt, bp,
                                     o_w2, o_b2, (float*)d_out, N);
}